// Round 8
// baseline (27066.525 us; speedup 1.0000x reference)
//
#include <hip/hip_runtime.h>
#include <hip/hip_bf16.h>

#define SEQ 1024
#define HID 2048
#define BAT 128
#define VOC 256
#define BN 48              // cols per block
#define NG 48              // col groups
#define MG 4               // row groups (128/32)
#define RING 5             // h ring slots (re-use period >> L2 lifetime)
#define RSTR 52            // reduce LDS row stride (dwords)
#define RWAVE 1664         // 32*52 dwords per wave slot

typedef __attribute__((ext_vector_type(4))) unsigned u32x4;
typedef __attribute__((ext_vector_type(8))) short short8;
typedef __attribute__((ext_vector_type(4))) float f32x4;

// counted vmem wait + scheduler fence (rule #18)
#define WAITVM(N) do { asm volatile("s_waitcnt vmcnt(" #N ")" ::: "memory"); \
                       __builtin_amdgcn_sched_barrier(0); } while (0)
// block barrier with LDS drain + compiler memory fence
#define BARRIER() asm volatile("s_waitcnt lgkmcnt(0)\n\ts_barrier" ::: "memory")

// --- asm memory ops (data-only paths; never address-forming) ----------------
__device__ __forceinline__ u32x4 ld16(const void* p) {          // cached L1/L2
    u32x4 r; asm volatile("global_load_dwordx4 %0, %1, off" : "=v"(r) : "v"(p)); return r;
}
__device__ __forceinline__ u32x4 ld16_coh(const void* p) {      // coherent (rare retry)
    u32x4 r; asm volatile("global_load_dwordx4 %0, %1, off sc0 sc1" : "=v"(r) : "v"(p)); return r;
}
__device__ __forceinline__ unsigned ld4_poll(const void* p) {   // fresh LLC read
    unsigned r;
    asm volatile("global_load_dword %0, %1, off sc0 sc1\n\ts_waitcnt vmcnt(0)"
                 : "=v"(r) : "v"(p) : "memory");
    return r;
}
// h-store: 8B atomic swap (no return) -> completes AT the LLC coherence point
__device__ __forceinline__ void swap8(void* p, unsigned long long v) {
    asm volatile("global_atomic_swap_x2 %0, %1, off" :: "v"(p), "v"(v) : "memory");
}
__device__ __forceinline__ void st16_nt(void* p, f32x4 v) {
    asm volatile("global_store_dwordx4 %0, %1, off nt" :: "v"(p), "v"(v) : "memory");
}

// --- bf16 helpers -----------------------------------------------------------
__device__ __forceinline__ unsigned short f2bf_rn(float v) {
    unsigned u = __float_as_uint(v);
    u += 0x7fffu + ((u >> 16) & 1u);
    return (unsigned short)(u >> 16);
}
__device__ __forceinline__ float bf2f(unsigned short s) {
    return __uint_as_float(((unsigned)s) << 16);
}
__device__ __forceinline__ unsigned packhl(float v) {
    unsigned short h = f2bf_rn(v);
    unsigned short l = f2bf_rn(v - bf2f(h));
    return ((unsigned)h << 16) | l;
}
// extract hi/lo bf16 pairs from two packed words (v_perm_b32)
__device__ __forceinline__ unsigned phi_(unsigned hi, unsigned lo) {
    return __builtin_amdgcn_perm(hi, lo, 0x07060302u);
}
__device__ __forceinline__ unsigned plo_(unsigned hi, unsigned lo) {
    return __builtin_amdgcn_perm(hi, lo, 0x05040100u);
}

// ---------------------------------------------------------------------------
// prologue: Wg[ng][96][2048] bf16 — rows 0..47 hi, 48..95 lo of 48 cols.
// ---------------------------------------------------------------------------
__global__ __launch_bounds__(256) void wsplit(
    const float* __restrict__ Whh, const float* __restrict__ Wlin,
    short* __restrict__ Wg)
{
    const int n  = blockIdx.x;          // 0..2303
    const int ng = n / BN, rl = n % BN;
    short* dhi = Wg + ((size_t)ng * 96 + rl) * HID;
    short* dlo = dhi + (size_t)BN * HID;
    for (int k = threadIdx.x; k < HID; k += 256) {
        float v = (n < HID) ? Whh[(size_t)k * HID + n]
                            : Wlin[(size_t)k * VOC + (n - HID)];
        unsigned short h = f2bf_rn(v);
        dhi[k] = (short)h;
        dlo[k] = (short)f2bf_rn(v - bf2f(h));
    }
}

// ---------------------------------------------------------------------------
// init: h0 -> packed u32 (hi<<16|lo) with tag bits cleared (step-0 tag == 0),
// ring slot 0; zero barrier counters.
// ---------------------------------------------------------------------------
__global__ __launch_bounds__(256) void hsplit(
    const float* __restrict__ h0, unsigned* __restrict__ hb,
    unsigned* __restrict__ cnt)
{
    if (blockIdx.x == 0 && threadIdx.x < MG)
        __hip_atomic_store(&cnt[threadIdx.x * 32], 0u, __ATOMIC_RELAXED,
                           __HIP_MEMORY_SCOPE_SYSTEM);
    for (int i = blockIdx.x * 256 + threadIdx.x; i < BAT * HID;
         i += gridDim.x * 256) {
        hb[i] = packhl(h0[i]) & ~3u;     // tag=0 in lo LSBs
    }
}

// ---------------------------------------------------------------------------
// persistent kernel. h ring: plain cached reads (L2 miss -> LLC serves fresh
// swap-written data); 4-bit step tag per 8B atomic granule catches any stale
// L2 survivor -> rare one-shot coherent retry. W from L2, register-direct.
// ---------------------------------------------------------------------------
__global__ __launch_bounds__(512, 1) void rnn_all(
    unsigned* __restrict__ hb, const short* __restrict__ Wg,
    const float* __restrict__ Wxh, const float* __restrict__ bh,
    const float* __restrict__ blin, const int* __restrict__ x,
    float* __restrict__ out, unsigned* __restrict__ cnt)
{
    __shared__ __align__(16) float red[8][RWAVE];

    const int tid  = threadIdx.x;
    const int wv   = tid >> 6, lane = tid & 63;
    const int l15  = lane & 15, lq = lane >> 4;
    const int ng   = blockIdx.x;           // 0..47 (ng%8 -> XCD spread)
    const int mg   = blockIdx.y;           // 0..3  (independent barrier domain)
    const int ks   = wv;                   // K-slice owner: [ks*256, ks*256+256)
    const short* Wgb = Wg + (size_t)ng * 96 * HID;
    const bool  has_y = (ng * BN + BN > HID);

    // epilogue element ownership: threads 0..383 own (row, 4 consecutive cols)
    const bool ep   = (tid < 384);
    const int  erow = ep ? (tid / 12) : 0;
    const int  ecol = ep ? ((tid % 12) * 4) : 0;
    const int  grow = mg * 32 + erow;
    const int  gcol = ng * BN + ecol;
    const bool ey   = ep && (gcol >= HID);
    const bool eh   = ep && (gcol <  HID);

    f32x4 add4 = {0.f, 0.f, 0.f, 0.f};
    f32x4 wx4  = {0.f, 0.f, 0.f, 0.f};
    if (eh) {
        add4 = *(const f32x4*)&bh[gcol];
        int xv0 = x[(size_t)grow * SEQ];
        wx4 = *(const f32x4*)&Wxh[(size_t)xv0 * HID + gcol];
    } else if (ey) {
        add4 = *(const f32x4*)&blin[gcol - HID];
    }

    u32x4 aA[3][2][2];   // [buf][mi][16B-half]   A: packed h, cached
    u32x4 bB[3][3][2];   // [buf][ni][hi/lo]      B: bf16 planes, cached

    auto issueB = [&](int k, int buf) {          // 6 loads
        const int kb = ks * 256 + k * 32;
        #pragma unroll
        for (int ni = 0; ni < 3; ++ni) {
            const short* p = Wgb + (size_t)(ni * 16 + l15) * HID + kb + lq * 8;
            bB[buf][ni][0] = ld16(p);
            bB[buf][ni][1] = ld16(p + (size_t)48 * HID);
        }
    };
    auto issueA = [&](const unsigned* Hp, int k, int buf) {   // 4 loads, CACHED
        const int kb = ks * 256 + k * 32;
        #pragma unroll
        for (int mi = 0; mi < 2; ++mi) {
            const unsigned* p = Hp + (size_t)(mg * 32 + mi * 16 + l15) * HID + kb + lq * 8;
            aA[buf][mi][0] = ld16(p);
            aA[buf][mi][1] = ld16(p + 4);
        }
    };
    // freshness check: every 8B swap-granule carries tag (w_even lo2 = T&3,
    // w_odd lo2 = T>>2). On any stale lane -> one-shot coherent refetch.
    auto checkA = [&](const unsigned* Hp, int k, int buf, unsigned Tlo, unsigned Thi) {
        int bad = 0;
        #pragma unroll
        for (int mi = 0; mi < 2; ++mi)
            #pragma unroll
            for (int hf = 0; hf < 2; ++hf) {
                u32x4 v = aA[buf][mi][hf];
                bad |= ((v[0] & 3u) != Tlo) | ((v[1] & 3u) != Thi)
                     | ((v[2] & 3u) != Tlo) | ((v[3] & 3u) != Thi);
            }
        if (__any(bad)) {
            const int kb = ks * 256 + k * 32;
            #pragma unroll
            for (int mi = 0; mi < 2; ++mi) {
                const unsigned* p = Hp + (size_t)(mg * 32 + mi * 16 + l15) * HID + kb + lq * 8;
                aA[buf][mi][0] = ld16_coh(p);
                aA[buf][mi][1] = ld16_coh(p + 4);
            }
            WAITVM(0);   // drain-all: later counted waits remain conservative
        }
    };

    issueB(0, 0); issueB(1, 1); issueB(2, 2);

    #pragma unroll 1
    for (int t = 0; ; ++t) {
        const bool last = (t == SEQ);
        if (last && !has_y) break;
        const unsigned* Hp = hb + (size_t)(t % RING) * BAT * HID;
        unsigned*       Hn = hb + (size_t)((t + 1) % RING) * BAT * HID;
        const unsigned  Tc  = (unsigned)(t & 15);
        const unsigned  Tlo = Tc & 3u, Thi = Tc >> 2;

        issueA(Hp, 0, 0); issueA(Hp, 1, 1); issueA(Hp, 2, 2);

        f32x4 acc[2][3];
        #pragma unroll
        for (int mi = 0; mi < 2; ++mi)
            #pragma unroll
            for (int ni = 0; ni < 3; ++ni)
                acc[mi][ni] = (f32x4){0.f, 0.f, 0.f, 0.f};

        // ---- K-loop: 8 kslots, 3-deep pipeline, counted vmcnt, no barriers
        #pragma unroll
        for (int k = 0; k < 8; ++k) {
            const int buf = k % 3;
            if (k == 0)      WAITVM(8);
            else if (k == 1) WAITVM(14);
            else if (k <= 5) WAITVM(20);
            else if (k == 6) WAITVM(10);
            else             WAITVM(0);
            checkA(Hp, k, buf, Tlo, Thi);
            #pragma unroll
            for (int mi = 0; mi < 2; ++mi) {
                u32x4 w0 = aA[buf][mi][0], w1 = aA[buf][mi][1];
                u32x4 ahw = { phi_(w0[1], w0[0]), phi_(w0[3], w0[2]),
                              phi_(w1[1], w1[0]), phi_(w1[3], w1[2]) };
                u32x4 alw = { plo_(w0[1], w0[0]), plo_(w0[3], w0[2]),
                              plo_(w1[1], w1[0]), plo_(w1[3], w1[2]) };
                short8 ah = __builtin_bit_cast(short8, ahw);
                short8 al = __builtin_bit_cast(short8, alw);
                #pragma unroll
                for (int ni = 0; ni < 3; ++ni) {
                    short8 bhv = __builtin_bit_cast(short8, bB[buf][ni][0]);
                    short8 blv = __builtin_bit_cast(short8, bB[buf][ni][1]);
                    acc[mi][ni] = __builtin_amdgcn_mfma_f32_16x16x32_bf16(ah, bhv, acc[mi][ni], 0, 0, 0);
                    acc[mi][ni] = __builtin_amdgcn_mfma_f32_16x16x32_bf16(ah, blv, acc[mi][ni], 0, 0, 0);
                    acc[mi][ni] = __builtin_amdgcn_mfma_f32_16x16x32_bf16(al, bhv, acc[mi][ni], 0, 0, 0);
                }
            }
            if (k < 5) { issueB(k + 3, buf); issueA(Hp, k + 3, buf); }
        }

        // next-step x/Wxh gather — plain loads (compiler-managed waits)
        f32x4 wxn = {0.f, 0.f, 0.f, 0.f};
        if (eh && !last) {
            const int tn = (t + 1 < SEQ) ? (t + 1) : (SEQ - 1);
            int xvn = x[(size_t)grow * SEQ + tn];
            wxn = *(const f32x4*)&Wxh[(size_t)xvn * HID + gcol];
        }

        // ---- cross-wave reduce (one barrier) -------------------------------
        #pragma unroll
        for (int mi = 0; mi < 2; ++mi)
            #pragma unroll
            for (int ni = 0; ni < 3; ++ni)
                #pragma unroll
                for (int r = 0; r < 4; ++r)
                    red[wv][(mi * 16 + lq * 4 + r) * RSTR + ni * 16 + l15] = acc[mi][ni][r];
        BARRIER();
        f32x4 sum = {0.f, 0.f, 0.f, 0.f};
        if (ep) {
            #pragma unroll
            for (int w = 0; w < 8; ++w)
                sum += *(const f32x4*)&red[w][erow * RSTR + ecol];
        }

        // ---- epilogue ------------------------------------------------------
        if (eh && !last) {
            const unsigned Tn  = (unsigned)((t + 1) & 15);
            const unsigned n0 = Tn & 3u, n1 = Tn >> 2;
            float th0 = tanhf(sum[0] + wx4[0] + add4[0]);
            float th1 = tanhf(sum[1] + wx4[1] + add4[1]);
            float th2 = tanhf(sum[2] + wx4[2] + add4[2]);
            float th3 = tanhf(sum[3] + wx4[3] + add4[3]);
            unsigned q0 = (packhl(th0) & ~3u) | n0;
            unsigned q1 = (packhl(th1) & ~3u) | n1;
            unsigned q2 = (packhl(th2) & ~3u) | n0;
            unsigned q3 = (packhl(th3) & ~3u) | n1;
            unsigned long long p01 = (unsigned long long)q0 | ((unsigned long long)q1 << 32);
            unsigned long long p23 = (unsigned long long)q2 | ((unsigned long long)q3 << 32);
            unsigned* hp = Hn + (size_t)grow * HID + gcol;
            swap8(hp, p01);
            swap8(hp + 2, p23);
            if (t == SEQ - 1) {
                f32x4 hv = {th0, th1, th2, th3};
                st16_nt(&out[(size_t)BAT * SEQ * VOC + (size_t)grow * HID + gcol], hv);
            }
        } else if (ey && t > 0) {
            st16_nt(&out[((size_t)grow * SEQ + (t - 1)) * VOC + (gcol - HID)], sum + add4);
        }

        if (last) break;
        wx4 = wxn;

        // next-step B prefetch rides across the barrier (W immutable)
        issueB(0, 0); issueB(1, 1); issueB(2, 2);
        WAITVM(18);                             // drains h/y stores; keeps 18 B
        BARRIER();

        // ---- mg-local grid barrier (48 blocks, private cache line) ---------
        if (tid == 0) {
            unsigned* c = &cnt[mg * 32];
            __hip_atomic_fetch_add(c, 1u, __ATOMIC_RELAXED, __HIP_MEMORY_SCOPE_AGENT);
            const unsigned target = 48u * (unsigned)(t + 1);
            int spins = 0;
            while (ld4_poll(c) < target) {
                __builtin_amdgcn_s_sleep(1);
                if (++spins > (1 << 22)) break;  // safety valve
            }
        }
        BARRIER();
    }
    WAITVM(0);
}

// ---------------------------------------------------------------------------
extern "C" void kernel_launch(void* const* d_in, const int* in_sizes, int n_in,
                              void* d_out, int out_size, void* d_ws, size_t ws_size,
                              hipStream_t stream) {
    const int*   x    = (const int*)  d_in[0];
    const float* h0   = (const float*)d_in[1];
    const float* Wxh  = (const float*)d_in[2];
    const float* Whh  = (const float*)d_in[3];
    const float* bh   = (const float*)d_in[4];
    const float* Wlin = (const float*)d_in[5];
    const float* blin = (const float*)d_in[6];
    float* out = (float*)d_out;

    // ws: Wg shorts [48*96*2048] | hb u32 [RING*128*2048] | cnt u32 [128]
    short*    Wg  = (short*)d_ws;
    unsigned* hb  = (unsigned*)(Wg + (size_t)NG * 96 * HID);
    unsigned* cnt = hb + (size_t)RING * BAT * HID;

    wsplit<<<dim3(HID + VOC), 256, 0, stream>>>(Whh, Wlin, Wg);
    hsplit<<<dim3(256), 256, 0, stream>>>(h0, hb, cnt);
    rnn_all<<<dim3(NG, MG), 512, 0, stream>>>(hb, Wg, Wxh, bh, blin, x, out, cnt);
}

// Round 9
// 23937.149 us; speedup vs baseline: 1.1307x; 1.1307x over previous
//
#include <hip/hip_runtime.h>
#include <hip/hip_bf16.h>

#define SEQ 1024
#define HID 2048
#define BAT 128
#define VOC 256
#define BN 48              // cols per block
#define NG 48              // col groups
#define MG 4               // row groups (128/32)
#define RING 6             // h ring slots; drift<=4 (rendezvous every 4 steps)
#define RSTR 52            // reduce LDS row stride (dwords)
#define RWAVE 1664         // 32*52 dwords per wave slot

typedef __attribute__((ext_vector_type(4))) unsigned u32x4;
typedef __attribute__((ext_vector_type(8))) short short8;
typedef __attribute__((ext_vector_type(4))) float f32x4;

// counted vmem wait + scheduler fence (rule #18)
#define WAITVM(N) do { asm volatile("s_waitcnt vmcnt(" #N ")" ::: "memory"); \
                       __builtin_amdgcn_sched_barrier(0); } while (0)
// block barrier with LDS drain + compiler memory fence
#define BARRIER() asm volatile("s_waitcnt lgkmcnt(0)\n\ts_barrier" ::: "memory")

// --- asm memory ops (data-only paths; never address-forming) ----------------
__device__ __forceinline__ u32x4 ld16(const void* p) {          // cached L1/L2
    u32x4 r; asm volatile("global_load_dwordx4 %0, %1, off" : "=v"(r) : "v"(p)); return r;
}
__device__ __forceinline__ u32x4 ld16_coh(const void* p) {      // bypass -> LLC
    u32x4 r; asm volatile("global_load_dwordx4 %0, %1, off sc0 sc1" : "=v"(r) : "v"(p)); return r;
}
__device__ __forceinline__ unsigned ld4_poll(const void* p) {   // fresh LLC read
    unsigned r;
    asm volatile("global_load_dword %0, %1, off sc0 sc1\n\ts_waitcnt vmcnt(0)"
                 : "=v"(r) : "v"(p) : "memory");
    return r;
}
// h-store: 8B atomic swap (no return) -> lands AT the LLC coherence point;
// the swap itself is the cross-XCD readiness signal (tag in lo bits).
__device__ __forceinline__ void swap8(void* p, unsigned long long v) {
    asm volatile("global_atomic_swap_x2 %0, %1, off" :: "v"(p), "v"(v) : "memory");
}
__device__ __forceinline__ void st16_nt(void* p, f32x4 v) {
    asm volatile("global_store_dwordx4 %0, %1, off nt" :: "v"(p), "v"(v) : "memory");
}

// --- bf16 helpers -----------------------------------------------------------
__device__ __forceinline__ unsigned short f2bf_rn(float v) {
    unsigned u = __float_as_uint(v);
    u += 0x7fffu + ((u >> 16) & 1u);
    return (unsigned short)(u >> 16);
}
__device__ __forceinline__ float bf2f(unsigned short s) {
    return __uint_as_float(((unsigned)s) << 16);
}
__device__ __forceinline__ unsigned packhl(float v) {
    unsigned short h = f2bf_rn(v);
    unsigned short l = f2bf_rn(v - bf2f(h));
    return ((unsigned)h << 16) | l;
}
// extract hi/lo bf16 pairs from two packed words (v_perm_b32)
__device__ __forceinline__ unsigned phi_(unsigned hi, unsigned lo) {
    return __builtin_amdgcn_perm(hi, lo, 0x07060302u);
}
__device__ __forceinline__ unsigned plo_(unsigned hi, unsigned lo) {
    return __builtin_amdgcn_perm(hi, lo, 0x05040100u);
}

// ---------------------------------------------------------------------------
// prologue: Wg[ng][96][2048] bf16 — rows 0..47 hi, 48..95 lo of 48 cols.
// ---------------------------------------------------------------------------
__global__ __launch_bounds__(256) void wsplit(
    const float* __restrict__ Whh, const float* __restrict__ Wlin,
    short* __restrict__ Wg)
{
    const int n  = blockIdx.x;          // 0..2303
    const int ng = n / BN, rl = n % BN;
    short* dhi = Wg + ((size_t)ng * 96 + rl) * HID;
    short* dlo = dhi + (size_t)BN * HID;
    for (int k = threadIdx.x; k < HID; k += 256) {
        float v = (n < HID) ? Whh[(size_t)k * HID + n]
                            : Wlin[(size_t)k * VOC + (n - HID)];
        unsigned short h = f2bf_rn(v);
        dhi[k] = (short)h;
        dlo[k] = (short)f2bf_rn(v - bf2f(h));
    }
}

// ---------------------------------------------------------------------------
// init: h0 -> packed u32 (hi<<16|lo), tag=0, ring slot 0; zero counters.
// ---------------------------------------------------------------------------
__global__ __launch_bounds__(256) void hsplit(
    const float* __restrict__ h0, unsigned* __restrict__ hb,
    unsigned* __restrict__ cnt)
{
    if (blockIdx.x == 0 && threadIdx.x < MG)
        __hip_atomic_store(&cnt[threadIdx.x * 32], 0u, __ATOMIC_RELAXED,
                           __HIP_MEMORY_SCOPE_SYSTEM);
    for (int i = blockIdx.x * 256 + threadIdx.x; i < BAT * HID;
         i += gridDim.x * 256) {
        hb[i] = packhl(h0[i]) & ~3u;     // tag=0 in lo LSBs
    }
}

// ---------------------------------------------------------------------------
// persistent kernel, barrier-free steady state: A-batches are tag-polled
// (producer's atomic swap IS the signal); an mg-local rendezvous every 4th
// step only protects ring-slot reuse (drift <= 4 < RING-1).
// ---------------------------------------------------------------------------
__global__ __launch_bounds__(512, 1) void rnn_all(
    unsigned* __restrict__ hb, const short* __restrict__ Wg,
    const float* __restrict__ Wxh, const float* __restrict__ bh,
    const float* __restrict__ blin, const int* __restrict__ x,
    float* __restrict__ out, unsigned* __restrict__ cnt)
{
    __shared__ __align__(16) float red[8][RWAVE];

    const int tid  = threadIdx.x;
    const int wv   = tid >> 6, lane = tid & 63;
    const int l15  = lane & 15, lq = lane >> 4;
    const int ng   = blockIdx.x;           // 0..47 (ng%8 -> XCD spread)
    const int mg   = blockIdx.y;           // 0..3  (independent sync domain)
    const int ks   = wv;                   // K-slice owner: [ks*256, ks*256+256)
    const short* Wgb = Wg + (size_t)ng * 96 * HID;
    const bool  has_y = (ng * BN + BN > HID);

    // epilogue element ownership: threads 0..383 own (row, 4 consecutive cols)
    const bool ep   = (tid < 384);
    const int  erow = ep ? (tid / 12) : 0;
    const int  ecol = ep ? ((tid % 12) * 4) : 0;
    const int  grow = mg * 32 + erow;
    const int  gcol = ng * BN + ecol;
    const bool ey   = ep && (gcol >= HID);
    const bool eh   = ep && (gcol <  HID);

    f32x4 add4 = {0.f, 0.f, 0.f, 0.f};
    f32x4 wx4  = {0.f, 0.f, 0.f, 0.f};
    if (eh) {
        add4 = *(const f32x4*)&bh[gcol];
        int xv0 = x[(size_t)grow * SEQ];
        wx4 = *(const f32x4*)&Wxh[(size_t)xv0 * HID + gcol];
    } else if (ey) {
        add4 = *(const f32x4*)&blin[gcol - HID];
    }

    u32x4 aA[3][2][2];   // [buf][mi][16B-half]   A: packed h, coherent
    u32x4 bB[3][3][2];   // [buf][ni][hi/lo]      B: bf16 planes, cached

    auto issueB = [&](int k, int buf) {          // 6 loads
        const int kb = ks * 256 + k * 32;
        #pragma unroll
        for (int ni = 0; ni < 3; ++ni) {
            const short* p = Wgb + (size_t)(ni * 16 + l15) * HID + kb + lq * 8;
            bB[buf][ni][0] = ld16(p);
            bB[buf][ni][1] = ld16(p + (size_t)48 * HID);
        }
    };
    auto issueA = [&](const unsigned* Hp, int k, int buf) {   // 4 loads, coherent
        const int kb = ks * 256 + k * 32;
        #pragma unroll
        for (int mi = 0; mi < 2; ++mi) {
            const unsigned* p = Hp + (size_t)(mg * 32 + mi * 16 + l15) * HID + kb + lq * 8;
            aA[buf][mi][0] = ld16_coh(p);
            aA[buf][mi][1] = ld16_coh(p + 4);
        }
    };
    // readiness poll: each 8B swap granule carries tag (even word lo2 = T&3,
    // odd word lo2 = T>>2). Refetch coherently until the producer's swap lands.
    auto pollA = [&](const unsigned* Hp, int k, int buf, unsigned Tlo, unsigned Thi) {
        const int kb = ks * 256 + k * 32;
        int iter = 0;
        for (;;) {
            int bad = 0;
            #pragma unroll
            for (int mi = 0; mi < 2; ++mi)
                #pragma unroll
                for (int hf = 0; hf < 2; ++hf) {
                    u32x4 v = aA[buf][mi][hf];
                    bad |= ((v[0] & 3u) != Tlo) | ((v[1] & 3u) != Thi)
                         | ((v[2] & 3u) != Tlo) | ((v[3] & 3u) != Thi);
                }
            if (!__any(bad) || ++iter > (1 << 20)) break;
            #pragma unroll
            for (int mi = 0; mi < 2; ++mi) {
                const unsigned* p = Hp + (size_t)(mg * 32 + mi * 16 + l15) * HID + kb + lq * 8;
                aA[buf][mi][0] = ld16_coh(p);
                aA[buf][mi][1] = ld16_coh(p + 4);
            }
            WAITVM(0);   // drain-all: later counted waits stay conservative
        }
    };

    issueB(0, 0); issueB(1, 1); issueB(2, 2);

    #pragma unroll 1
    for (int t = 0; ; ++t) {
        const bool last = (t == SEQ);
        if (last && !has_y) break;
        const unsigned* Hp = hb + (size_t)(t % RING) * BAT * HID;
        unsigned*       Hn = hb + (size_t)((t + 1) % RING) * BAT * HID;
        const unsigned  Tc  = (unsigned)(t & 15);
        const unsigned  Tlo = Tc & 3u, Thi = Tc >> 2;

        issueA(Hp, 0, 0); issueA(Hp, 1, 1); issueA(Hp, 2, 2);

        f32x4 acc[2][3];
        #pragma unroll
        for (int mi = 0; mi < 2; ++mi)
            #pragma unroll
            for (int ni = 0; ni < 3; ++ni)
                acc[mi][ni] = (f32x4){0.f, 0.f, 0.f, 0.f};

        // ---- K-loop: 8 kslots, 3-deep pipeline, counted vmcnt, tag-polled
        #pragma unroll
        for (int k = 0; k < 8; ++k) {
            const int buf = k % 3;
            if (k == 0)      WAITVM(8);
            else if (k == 1) WAITVM(14);
            else if (k <= 5) WAITVM(20);
            else if (k == 6) WAITVM(10);
            else             WAITVM(0);
            pollA(Hp, k, buf, Tlo, Thi);
            #pragma unroll
            for (int mi = 0; mi < 2; ++mi) {
                u32x4 w0 = aA[buf][mi][0], w1 = aA[buf][mi][1];
                u32x4 ahw = { phi_(w0[1], w0[0]), phi_(w0[3], w0[2]),
                              phi_(w1[1], w1[0]), phi_(w1[3], w1[2]) };
                u32x4 alw = { plo_(w0[1], w0[0]), plo_(w0[3], w0[2]),
                              plo_(w1[1], w1[0]), plo_(w1[3], w1[2]) };
                short8 ah = __builtin_bit_cast(short8, ahw);
                short8 al = __builtin_bit_cast(short8, alw);
                #pragma unroll
                for (int ni = 0; ni < 3; ++ni) {
                    short8 bhv = __builtin_bit_cast(short8, bB[buf][ni][0]);
                    short8 blv = __builtin_bit_cast(short8, bB[buf][ni][1]);
                    acc[mi][ni] = __builtin_amdgcn_mfma_f32_16x16x32_bf16(ah, bhv, acc[mi][ni], 0, 0, 0);
                    acc[mi][ni] = __builtin_amdgcn_mfma_f32_16x16x32_bf16(ah, blv, acc[mi][ni], 0, 0, 0);
                    acc[mi][ni] = __builtin_amdgcn_mfma_f32_16x16x32_bf16(al, bhv, acc[mi][ni], 0, 0, 0);
                }
            }
            if (k < 5) { issueB(k + 3, buf); issueA(Hp, k + 3, buf); }
        }

        // next-step x/Wxh gather — plain loads (compiler-managed waits)
        f32x4 wxn = {0.f, 0.f, 0.f, 0.f};
        if (eh && !last) {
            const int tn = (t + 1 < SEQ) ? (t + 1) : (SEQ - 1);
            int xvn = x[(size_t)grow * SEQ + tn];
            wxn = *(const f32x4*)&Wxh[(size_t)xvn * HID + gcol];
        }

        // ---- cross-wave reduce (one block barrier) -------------------------
        #pragma unroll
        for (int mi = 0; mi < 2; ++mi)
            #pragma unroll
            for (int ni = 0; ni < 3; ++ni)
                #pragma unroll
                for (int r = 0; r < 4; ++r)
                    red[wv][(mi * 16 + lq * 4 + r) * RSTR + ni * 16 + l15] = acc[mi][ni][r];
        BARRIER();
        f32x4 sum = {0.f, 0.f, 0.f, 0.f};
        if (ep) {
            #pragma unroll
            for (int w = 0; w < 8; ++w)
                sum += *(const f32x4*)&red[w][erow * RSTR + ecol];
        }

        // ---- epilogue: swaps carry data + tag (the readiness signal) -------
        if (eh && !last) {
            const unsigned Tn = (unsigned)((t + 1) & 15);
            const unsigned n0 = Tn & 3u, n1 = Tn >> 2;
            float th0 = tanhf(sum[0] + wx4[0] + add4[0]);
            float th1 = tanhf(sum[1] + wx4[1] + add4[1]);
            float th2 = tanhf(sum[2] + wx4[2] + add4[2]);
            float th3 = tanhf(sum[3] + wx4[3] + add4[3]);
            unsigned q0 = (packhl(th0) & ~3u) | n0;
            unsigned q1 = (packhl(th1) & ~3u) | n1;
            unsigned q2 = (packhl(th2) & ~3u) | n0;
            unsigned q3 = (packhl(th3) & ~3u) | n1;
            unsigned long long p01 = (unsigned long long)q0 | ((unsigned long long)q1 << 32);
            unsigned long long p23 = (unsigned long long)q2 | ((unsigned long long)q3 << 32);
            unsigned* hp = Hn + (size_t)grow * HID + gcol;
            swap8(hp, p01);
            swap8(hp + 2, p23);
            if (t == SEQ - 1) {
                f32x4 hv = {th0, th1, th2, th3};
                st16_nt(&out[(size_t)BAT * SEQ * VOC + (size_t)grow * HID + gcol], hv);
            }
        } else if (ey && t > 0) {
            st16_nt(&out[((size_t)grow * SEQ + (t - 1)) * VOC + (gcol - HID)], sum + add4);
        }

        if (last) break;
        wx4 = wxn;

        // next-step B prefetch (W immutable; stays in flight into the K-loop)
        issueB(0, 0); issueB(1, 1); issueB(2, 2);

        // ---- rendezvous every 4th step: ring-reuse protection only ---------
        // At end of step t (t%4==3) all 48 mg-blocks sync -> drift <= 4 < RING-1.
        // tid0 stalls here; the next step's reduce-BARRIER gates the whole
        // block before its next WRITE, so no extra barrier is needed.
        if ((t & 3) == 3 && tid == 0) {
            unsigned* c = &cnt[mg * 32];
            __hip_atomic_fetch_add(c, 1u, __ATOMIC_RELAXED, __HIP_MEMORY_SCOPE_AGENT);
            const unsigned target = 48u * (unsigned)((t + 1) >> 2);
            int spins = 0;
            while (ld4_poll(c) < target) {
                __builtin_amdgcn_s_sleep(4);
                if (++spins > (1 << 20)) break;  // safety valve
            }
        }
    }
    WAITVM(0);
}

// ---------------------------------------------------------------------------
extern "C" void kernel_launch(void* const* d_in, const int* in_sizes, int n_in,
                              void* d_out, int out_size, void* d_ws, size_t ws_size,
                              hipStream_t stream) {
    const int*   x    = (const int*)  d_in[0];
    const float* h0   = (const float*)d_in[1];
    const float* Wxh  = (const float*)d_in[2];
    const float* Whh  = (const float*)d_in[3];
    const float* bh   = (const float*)d_in[4];
    const float* Wlin = (const float*)d_in[5];
    const float* blin = (const float*)d_in[6];
    float* out = (float*)d_out;

    // ws: Wg shorts [48*96*2048] | hb u32 [RING*128*2048] | cnt u32 [128]
    short*    Wg  = (short*)d_ws;
    unsigned* hb  = (unsigned*)(Wg + (size_t)NG * 96 * HID);
    unsigned* cnt = hb + (size_t)RING * BAT * HID;

    wsplit<<<dim3(HID + VOC), 256, 0, stream>>>(Whh, Wlin, Wg);
    hsplit<<<dim3(256), 256, 0, stream>>>(h0, hb, cnt);
    rnn_all<<<dim3(NG, MG), 512, 0, stream>>>(hb, Wg, Wxh, bh, blin, x, out, cnt);
}

// Round 10
// 18560.980 us; speedup vs baseline: 1.4582x; 1.2896x over previous
//
#include <hip/hip_runtime.h>
#include <hip/hip_bf16.h>

#define SEQ 1024
#define HID 2048
#define BAT 128
#define VOC 256
#define BN 48              // cols per block
#define NG 48              // col groups
#define MG 4               // row groups (128/32)
#define RING 3             // h ring slots (barrier-ordered)
#define RSTR 52            // reduce LDS row stride (dwords)
#define RWAVE 1664         // 32*52 dwords per wave slot

typedef __attribute__((ext_vector_type(4))) unsigned u32x4;
typedef __attribute__((ext_vector_type(8))) short short8;
typedef __attribute__((ext_vector_type(4))) float f32x4;

// counted vmem wait + scheduler fence (rule #18)
#define WAITVM(N) do { asm volatile("s_waitcnt vmcnt(" #N ")" ::: "memory"); \
                       __builtin_amdgcn_sched_barrier(0); } while (0)
// block barrier with LDS drain + compiler memory fence
#define BARRIER() asm volatile("s_waitcnt lgkmcnt(0)\n\ts_barrier" ::: "memory")

// --- asm memory ops (data-only paths; never address-forming) ----------------
__device__ __forceinline__ u32x4 ld16(const void* p) {          // cached L1/L2
    u32x4 r; asm volatile("global_load_dwordx4 %0, %1, off" : "=v"(r) : "v"(p)); return r;
}
__device__ __forceinline__ u32x4 ld16_coh(const void* p) {      // bypass -> LLC
    u32x4 r; asm volatile("global_load_dwordx4 %0, %1, off sc0 sc1" : "=v"(r) : "v"(p)); return r;
}
__device__ __forceinline__ unsigned ld4_poll(const void* p) {   // fresh LLC read
    unsigned r;
    asm volatile("global_load_dword %0, %1, off sc0 sc1\n\ts_waitcnt vmcnt(0)"
                 : "=v"(r) : "v"(p) : "memory");
    return r;
}
// h-store: 8B atomic swap (no return) -> completes AT the LLC coherence point
__device__ __forceinline__ void swap8(void* p, unsigned long long v) {
    asm volatile("global_atomic_swap_x2 %0, %1, off" :: "v"(p), "v"(v) : "memory");
}
__device__ __forceinline__ void st16_nt(void* p, f32x4 v) {
    asm volatile("global_store_dwordx4 %0, %1, off nt" :: "v"(p), "v"(v) : "memory");
}

// --- bf16 helpers -----------------------------------------------------------
__device__ __forceinline__ unsigned short f2bf_rn(float v) {
    unsigned u = __float_as_uint(v);
    u += 0x7fffu + ((u >> 16) & 1u);
    return (unsigned short)(u >> 16);
}
__device__ __forceinline__ float bf2f(unsigned short s) {
    return __uint_as_float(((unsigned)s) << 16);
}

// ---------------------------------------------------------------------------
// prologue: Wg[ng][96][2048] bf16 — rows 0..47 hi, 48..95 lo of 48 cols.
// (W keeps hi+lo split: its quantization error would otherwise dominate.)
// ---------------------------------------------------------------------------
__global__ __launch_bounds__(256) void wsplit(
    const float* __restrict__ Whh, const float* __restrict__ Wlin,
    short* __restrict__ Wg)
{
    const int n  = blockIdx.x;          // 0..2303
    const int ng = n / BN, rl = n % BN;
    short* dhi = Wg + ((size_t)ng * 96 + rl) * HID;
    short* dlo = dhi + (size_t)BN * HID;
    for (int k = threadIdx.x; k < HID; k += 256) {
        float v = (n < HID) ? Whh[(size_t)k * HID + n]
                            : Wlin[(size_t)k * VOC + (n - HID)];
        unsigned short h = f2bf_rn(v);
        dhi[k] = (short)h;
        dlo[k] = (short)f2bf_rn(v - bf2f(h));
    }
}

// ---------------------------------------------------------------------------
// init: h0 -> plain bf16, ring slot 0; zero barrier counters.
// ---------------------------------------------------------------------------
__global__ __launch_bounds__(256) void hsplit(
    const float* __restrict__ h0, unsigned short* __restrict__ hb,
    unsigned* __restrict__ cnt)
{
    if (blockIdx.x == 0 && threadIdx.x < MG)
        __hip_atomic_store(&cnt[threadIdx.x * 32], 0u, __ATOMIC_RELAXED,
                           __HIP_MEMORY_SCOPE_SYSTEM);
    for (int i = blockIdx.x * 256 + threadIdx.x; i < BAT * HID;
         i += gridDim.x * 256) {
        hb[i] = f2bf_rn(h0[i]);
    }
}

// ---------------------------------------------------------------------------
// persistent kernel: h as plain bf16 (halves the coherent-path traffic —
// the r9-identified bottleneck). 2-MFMA scheme: ah*bh + ah*bl (W split,
// h single plane). r7 barrier structure (deterministic, no tags needed).
// ---------------------------------------------------------------------------
__global__ __launch_bounds__(512, 1) void rnn_all(
    unsigned short* __restrict__ hb, const short* __restrict__ Wg,
    const float* __restrict__ Wxh, const float* __restrict__ bh,
    const float* __restrict__ blin, const int* __restrict__ x,
    float* __restrict__ out, unsigned* __restrict__ cnt)
{
    __shared__ __align__(16) float red[8][RWAVE];

    const int tid  = threadIdx.x;
    const int wv   = tid >> 6, lane = tid & 63;
    const int l15  = lane & 15, lq = lane >> 4;
    const int ng   = blockIdx.x;           // 0..47 (ng%8 -> XCD spread)
    const int mg   = blockIdx.y;           // 0..3  (independent sync domain)
    const int ks   = wv;                   // K-slice owner: [ks*256, ks*256+256)
    const short* Wgb = Wg + (size_t)ng * 96 * HID;
    const bool  has_y = (ng * BN + BN > HID);

    // epilogue element ownership: threads 0..383 own (row, 4 consecutive cols)
    const bool ep   = (tid < 384);
    const int  erow = ep ? (tid / 12) : 0;
    const int  ecol = ep ? ((tid % 12) * 4) : 0;
    const int  grow = mg * 32 + erow;
    const int  gcol = ng * BN + ecol;
    const bool ey   = ep && (gcol >= HID);
    const bool eh   = ep && (gcol <  HID);

    f32x4 add4 = {0.f, 0.f, 0.f, 0.f};
    f32x4 wx4  = {0.f, 0.f, 0.f, 0.f};
    if (eh) {
        add4 = *(const f32x4*)&bh[gcol];
        int xv0 = x[(size_t)grow * SEQ];
        wx4 = *(const f32x4*)&Wxh[(size_t)xv0 * HID + gcol];
    } else if (ey) {
        add4 = *(const f32x4*)&blin[gcol - HID];
    }

    u32x4 aA[3][2];      // [buf][mi]       A: bf16 h, coherent (1 load each)
    u32x4 bB[3][3][2];   // [buf][ni][hi/lo] B: bf16 planes, cached

    auto issueB = [&](int k, int buf) {          // 6 loads
        const int kb = ks * 256 + k * 32;
        #pragma unroll
        for (int ni = 0; ni < 3; ++ni) {
            const short* p = Wgb + (size_t)(ni * 16 + l15) * HID + kb + lq * 8;
            bB[buf][ni][0] = ld16(p);
            bB[buf][ni][1] = ld16(p + (size_t)48 * HID);
        }
    };
    auto issueA = [&](const unsigned short* Hp, int k, int buf) {  // 2 loads
        const int kb = ks * 256 + k * 32;
        #pragma unroll
        for (int mi = 0; mi < 2; ++mi) {
            const unsigned short* p =
                Hp + (size_t)(mg * 32 + mi * 16 + l15) * HID + kb + lq * 8;
            aA[buf][mi] = ld16_coh(p);
        }
    };

    // prologue prefetch: B batches 0..2 (18 ops), then per-step A at loop top
    issueB(0, 0); issueB(1, 1); issueB(2, 2);

    #pragma unroll 1
    for (int t = 0; ; ++t) {
        const bool last = (t == SEQ);
        if (last && !has_y) break;
        const unsigned short* Hp = hb + (size_t)(t % RING) * BAT * HID;
        unsigned short*       Hn = hb + (size_t)((t + 1) % RING) * BAT * HID;

        issueA(Hp, 0, 0); issueA(Hp, 1, 1); issueA(Hp, 2, 2);   // 6 ops

        f32x4 acc[2][3];
        #pragma unroll
        for (int mi = 0; mi < 2; ++mi)
            #pragma unroll
            for (int ni = 0; ni < 3; ++ni)
                acc[mi][ni] = (f32x4){0.f, 0.f, 0.f, 0.f};

        // ---- K-loop: 8 batches (6B+2A each), 3-deep pipeline, counted vmcnt
        #pragma unroll
        for (int k = 0; k < 8; ++k) {
            const int buf = k % 3;
            if (k == 0)      WAITVM(4);     // A0 done (A1,A2 in flight)
            else if (k == 1) WAITVM(10);    // A1 done (A2,B3,A3 in flight)
            else if (k <= 5) WAITVM(16);    // batch k done (k+1,k+2 in flight)
            else if (k == 6) WAITVM(8);
            else             WAITVM(0);
            #pragma unroll
            for (int mi = 0; mi < 2; ++mi) {
                short8 ah = __builtin_bit_cast(short8, aA[buf][mi]);
                #pragma unroll
                for (int ni = 0; ni < 3; ++ni) {
                    short8 bhv = __builtin_bit_cast(short8, bB[buf][ni][0]);
                    short8 blv = __builtin_bit_cast(short8, bB[buf][ni][1]);
                    acc[mi][ni] = __builtin_amdgcn_mfma_f32_16x16x32_bf16(ah, bhv, acc[mi][ni], 0, 0, 0);
                    acc[mi][ni] = __builtin_amdgcn_mfma_f32_16x16x32_bf16(ah, blv, acc[mi][ni], 0, 0, 0);
                }
            }
            if (k < 5) { issueB(k + 3, buf); issueA(Hp, k + 3, buf); }
        }

        // next-step x/Wxh gather — plain loads (compiler-managed waits)
        f32x4 wxn = {0.f, 0.f, 0.f, 0.f};
        if (eh && !last) {
            const int tn = (t + 1 < SEQ) ? (t + 1) : (SEQ - 1);
            int xvn = x[(size_t)grow * SEQ + tn];
            wxn = *(const f32x4*)&Wxh[(size_t)xvn * HID + gcol];
        }

        // ---- cross-wave reduce (one block barrier) -------------------------
        #pragma unroll
        for (int mi = 0; mi < 2; ++mi)
            #pragma unroll
            for (int ni = 0; ni < 3; ++ni)
                #pragma unroll
                for (int r = 0; r < 4; ++r)
                    red[wv][(mi * 16 + lq * 4 + r) * RSTR + ni * 16 + l15] = acc[mi][ni][r];
        BARRIER();
        f32x4 sum = {0.f, 0.f, 0.f, 0.f};
        if (ep) {
            #pragma unroll
            for (int w = 0; w < 8; ++w)
                sum += *(const f32x4*)&red[w][erow * RSTR + ecol];
        }

        // ---- epilogue ------------------------------------------------------
        if (eh && !last) {
            float th0 = tanhf(sum[0] + wx4[0] + add4[0]);
            float th1 = tanhf(sum[1] + wx4[1] + add4[1]);
            float th2 = tanhf(sum[2] + wx4[2] + add4[2]);
            float th3 = tanhf(sum[3] + wx4[3] + add4[3]);
            unsigned long long q =
                  (unsigned long long)f2bf_rn(th0)
                | ((unsigned long long)f2bf_rn(th1) << 16)
                | ((unsigned long long)f2bf_rn(th2) << 32)
                | ((unsigned long long)f2bf_rn(th3) << 48);
            swap8(Hn + (size_t)grow * HID + gcol, q);
            if (t == SEQ - 1) {
                f32x4 hv = {th0, th1, th2, th3};
                st16_nt(&out[(size_t)BAT * SEQ * VOC + (size_t)grow * HID + gcol], hv);
            }
        } else if (ey && t > 0) {
            st16_nt(&out[((size_t)grow * SEQ + (t - 1)) * VOC + (gcol - HID)], sum + add4);
        }

        if (last) break;
        wx4 = wxn;

        // next-step B prefetch rides across the barrier (W immutable)
        issueB(0, 0); issueB(1, 1); issueB(2, 2);
        WAITVM(18);                             // drains h/y stores; keeps 18 B
        BARRIER();

        // ---- mg-local grid barrier (48 blocks, private cache line) ---------
        if (tid == 0) {
            unsigned* c = &cnt[mg * 32];
            __hip_atomic_fetch_add(c, 1u, __ATOMIC_RELAXED, __HIP_MEMORY_SCOPE_AGENT);
            const unsigned target = 48u * (unsigned)(t + 1);
            int spins = 0;
            while (ld4_poll(c) < target) {
                __builtin_amdgcn_s_sleep(1);
                if (++spins > (1 << 22)) break;  // safety valve
            }
        }
        BARRIER();
    }
    WAITVM(0);
}

// ---------------------------------------------------------------------------
extern "C" void kernel_launch(void* const* d_in, const int* in_sizes, int n_in,
                              void* d_out, int out_size, void* d_ws, size_t ws_size,
                              hipStream_t stream) {
    const int*   x    = (const int*)  d_in[0];
    const float* h0   = (const float*)d_in[1];
    const float* Wxh  = (const float*)d_in[2];
    const float* Whh  = (const float*)d_in[3];
    const float* bh   = (const float*)d_in[4];
    const float* Wlin = (const float*)d_in[5];
    const float* blin = (const float*)d_in[6];
    float* out = (float*)d_out;

    // ws: Wg shorts [48*96*2048] | hb bf16 [RING*128*2048] | cnt u32 [128]
    short*          Wg  = (short*)d_ws;
    unsigned short* hb  = (unsigned short*)(Wg + (size_t)NG * 96 * HID);
    unsigned*       cnt = (unsigned*)(hb + (size_t)RING * BAT * HID);

    wsplit<<<dim3(HID + VOC), 256, 0, stream>>>(Whh, Wlin, Wg);
    hsplit<<<dim3(256), 256, 0, stream>>>(h0, hb, cnt);
    rnn_all<<<dim3(NG, MG), 512, 0, stream>>>(hb, Wg, Wxh, bh, blin, x, out, cnt);
}